// Round 1
// baseline (371.809 us; speedup 1.0000x reference)
//
#include <hip/hip_runtime.h>

using short8   = __attribute__((ext_vector_type(8))) short;
using f32x4    = __attribute__((ext_vector_type(4))) float;
using ushort4v = __attribute__((ext_vector_type(4))) unsigned short;

#define BN_EPS 1e-5f
// log2(e)/sqrt(32): folded into q projection so softmax uses native exp2
#define ATT_SCALE_LOG2E 0.2550348347988049f

__device__ __forceinline__ unsigned short f2bf(float f) {
    union { float f; unsigned u; } v; v.f = f;
    return (unsigned short)((v.u + 0x7FFFu + ((v.u >> 16) & 1u)) >> 16);  // RNE
}

// pack two f32 -> two bf16 (round-half-up): a in low 16, b in high 16
__device__ __forceinline__ unsigned pack2bf(float a, float b) {
    union { float f; unsigned u; } ua, ub; ua.f = a; ub.f = b;
    return __builtin_amdgcn_perm(ub.u + 0x8000u, ua.u + 0x8000u, 0x07060302u);
}

// ---------------------------------------------------------------------------
// Kernel 0: weights -> bf16; fold conv-bias + BN into per-row (scale, offset).
// Rows: 0-31 q, 32-63 k, 64-319 v.
// ---------------------------------------------------------------------------
__global__ void prep_kernel(
    const float* __restrict__ qw, const float* __restrict__ qb,
    const float* __restrict__ qg, const float* __restrict__ qbe,
    const float* __restrict__ qm, const float* __restrict__ qv,
    const float* __restrict__ kw, const float* __restrict__ kb,
    const float* __restrict__ kg, const float* __restrict__ kbe,
    const float* __restrict__ km, const float* __restrict__ kvv,
    const float* __restrict__ vw, const float* __restrict__ vb,
    const float* __restrict__ vg, const float* __restrict__ vbe,
    const float* __restrict__ vm, const float* __restrict__ vv,
    unsigned short* __restrict__ wq, float* __restrict__ scale,
    float* __restrict__ off)
{
    int r = blockIdx.x;      // 0..319
    int t = threadIdx.x;     // 0..63
    const float *wsrc, *g, *be, *mn, *vr, *bi;
    int rl;
    if (r < 32)      { rl = r;      wsrc = qw; g = qg; be = qbe; mn = qm; vr = qv;  bi = qb; }
    else if (r < 64) { rl = r - 32; wsrc = kw; g = kg; be = kbe; mn = km; vr = kvv; bi = kb; }
    else             { rl = r - 64; wsrc = vw; g = vg; be = vbe; mn = vm; vr = vv;  bi = vb; }

    float4 w4 = *(const float4*)(wsrc + rl * 256 + t * 4);
    ushort4v o;
    o.x = f2bf(w4.x); o.y = f2bf(w4.y); o.z = f2bf(w4.z); o.w = f2bf(w4.w);
    *(ushort4v*)(wq + r * 256 + t * 4) = o;

    if (t == 0) {
        float inv = g[rl] * rsqrtf(vr[rl] + BN_EPS);
        float ofv = bi[rl] * inv + be[rl] - mn[rl] * inv;
        float s = (r < 32) ? ATT_SCALE_LOG2E : 1.0f;
        scale[r] = inv * s;
        off[r]   = ofv * s;
    }
}

// ---------------------------------------------------------------------------
// Kernel 1: projections. bx = ((b*64+nt)<<2) | g ; g=0: q(x1), g=1: k(x2),
// g=2: v rows 0-127 (x2), g=3: v rows 128-255 (x2).
// q_t/k_t: [b][n][32] bf16.  v_ws: TILE-BLOCKED [b*64+nt][256][64] bf16.
// ---------------------------------------------------------------------------
#define XT_PITCH 264

__global__ __launch_bounds__(256, 4) void proj_kernel(
    const float* __restrict__ x1, const float* __restrict__ x2,
    const unsigned short* __restrict__ wq,
    const float* __restrict__ scale, const float* __restrict__ off,
    unsigned short* __restrict__ q_t, unsigned short* __restrict__ k_t,
    unsigned short* __restrict__ v_ws)
{
    __shared__ __align__(16) unsigned short Xt[64 * XT_PITCH];   // 33792 B
    int bx = blockIdx.x;
    int g  = bx & 3;
    int t2 = bx >> 2;
    int nt = t2 & 63;
    int b  = t2 >> 6;
    int n0 = nt * 64;
    int tid = threadIdx.x;
    int wv = tid >> 6, lane = tid & 63;
    int m16 = lane & 15, qd = lane >> 4;

    const float* xb = ((g == 0) ? x1 : x2) + (size_t)b * 256 * 4096 + n0 + lane;

    // octet-gather transpose: n = lane, channels 8*o..8*o+7, o = wv*8+i
    #pragma unroll 2
    for (int i = 0; i < 8; ++i) {
        int o = wv * 8 + i;                       // 0..31
        const float* src = xb + (size_t)(o * 8) * 4096;
        uint4 dw;
        dw.x = pack2bf(src[0],                src[(size_t)1 * 4096]);
        dw.y = pack2bf(src[(size_t)2 * 4096], src[(size_t)3 * 4096]);
        dw.z = pack2bf(src[(size_t)4 * 4096], src[(size_t)5 * 4096]);
        dw.w = pack2bf(src[(size_t)6 * 4096], src[(size_t)7 * 4096]);
        *(uint4*)&Xt[lane * XT_PITCH + o * 8] = dw;
    }
    __syncthreads();

    f32x4 zero4 = {0.f, 0.f, 0.f, 0.f};

    if (g < 2) {
        int rb = g * 32;
        f32x4 acc0 = zero4, acc1 = zero4;
        #pragma unroll 2
        for (int s = 0; s < 8; ++s) {
            short8 w0 = *(const short8*)(wq + (size_t)(rb +      m16) * 256 + s * 32 + qd * 8);
            short8 w1 = *(const short8*)(wq + (size_t)(rb + 16 + m16) * 256 + s * 32 + qd * 8);
            short8 xf = *(const short8*)&Xt[(16 * wv + m16) * XT_PITCH + s * 32 + qd * 8];
            acc0 = __builtin_amdgcn_mfma_f32_16x16x32_bf16(w0, xf, acc0, 0, 0, 0);
            acc1 = __builtin_amdgcn_mfma_f32_16x16x32_bf16(w1, xf, acc1, 0, 0, 0);
        }
        unsigned short* dst = (g == 0) ? q_t : k_t;
        int ncol = n0 + 16 * wv + m16;
        #pragma unroll
        for (int tm = 0; tm < 2; ++tm) {
            f32x4 acc = tm ? acc1 : acc0;
            int r0 = 16 * tm + 4 * qd;
            float4 sc = *(const float4*)(scale + rb + r0);
            float4 of = *(const float4*)(off   + rb + r0);
            ushort4v o;
            o.x = f2bf(acc.x * sc.x + of.x);
            o.y = f2bf(acc.y * sc.y + of.y);
            o.z = f2bf(acc.z * sc.z + of.z);
            o.w = f2bf(acc.w * sc.w + of.w);
            *(ushort4v*)(dst + ((size_t)b * 4096 + ncol) * 32 + r0) = o;
        }
    } else {
        int cb = (g - 2) * 128;
        f32x4 acc[2][4];
        #pragma unroll
        for (int rr = 0; rr < 2; ++rr)
            #pragma unroll
            for (int tm = 0; tm < 4; ++tm) acc[rr][tm] = zero4;
        #pragma unroll 2
        for (int s = 0; s < 8; ++s) {
            short8 xf[4];
            #pragma unroll
            for (int tm = 0; tm < 4; ++tm)
                xf[tm] = *(const short8*)&Xt[(16 * tm + m16) * XT_PITCH + s * 32 + qd * 8];
            #pragma unroll
            for (int rr = 0; rr < 2; ++rr) {
                short8 wf = *(const short8*)(wq + (size_t)(64 + cb + rr * 64 + 16 * wv + m16) * 256 + s * 32 + qd * 8);
                #pragma unroll
                for (int tm = 0; tm < 4; ++tm)
                    acc[rr][tm] = __builtin_amdgcn_mfma_f32_16x16x32_bf16(xf[tm], wf, acc[rr][tm], 0, 0, 0);
            }
        }
        unsigned short* vt = v_ws + (size_t)(b * 64 + nt) * 256 * 64;
        #pragma unroll
        for (int rr = 0; rr < 2; ++rr) {
            int c = cb + rr * 64 + 16 * wv + m16;
            float sc = scale[64 + c], of = off[64 + c];
            #pragma unroll
            for (int tm = 0; tm < 4; ++tm) {
                int nloc = 16 * tm + 4 * qd;
                ushort4v o;
                o.x = f2bf(acc[rr][tm].x * sc + of);
                o.y = f2bf(acc[rr][tm].y * sc + of);
                o.z = f2bf(acc[rr][tm].z * sc + of);
                o.w = f2bf(acc[rr][tm].w * sc + of);
                *(ushort4v*)(vt + c * 64 + nloc) = o;
            }
        }
    }
}

// ---------------------------------------------------------------------------
// Kernel 2: flash attention, SOFTMAX SHARED ACROSS ALL 256 CHANNELS.
// Block = 8 waves (512 thr) owning (b, 32-query tile); grid 4*128 = 512,
// XCD-bijectively swizzled so each XCD serves one batch (V+K L2-resident).
// Per 64-key tile:
//   QK phase : wave (qsub=wv>>2, ksub=wv&3) computes ONE 16k x 16q S tile
//              (dqk=32 -> single MFMA), 4x exp2/lane, packs to bf16 and
//              writes a shared XOR-swizzled P buffer [2qsub][16q][64k].
//   barrier  : P double-buffered -> exactly one __syncthreads per tile.
//   PV phase : wave (qsub, csub=wv&3) reads its q-half of P (conflict-free
//              swizzled b128) and does 8 MFMAs vs V frags loaded DIRECTLY
//              from global (L2-resident; no LDS staging at all). K frag is
//              one perfectly-coalesced 1KB wave load, prefetched 1 tile.
// Softmax/QK redundancy: 4x -> 1x (algorithmic minimum). LDS: 32KB -> 8.7KB.
// Row sums kept per (ksub) wave in registers; combined once via LDS at end.
// ---------------------------------------------------------------------------
__global__ __launch_bounds__(512, 4) void flash_kernel(
    const unsigned short* __restrict__ q_t, const unsigned short* __restrict__ k_t,
    const unsigned short* __restrict__ v_ws, float* __restrict__ out)
{
    __shared__ __align__(16) unsigned short Pb[2][2][1024];  // [z][qsub][16q*64k] 8KB
    __shared__ __align__(16) float Ls[2][4][16];             // [qsub][ksub][q] 512B

    int phys = blockIdx.x;                 // 512 blocks
    int xcd  = phys & 7, loc = phys >> 3;  // bijective XCD swizzle (512 = 8*64)
    int b    = xcd & 3;
    int qt   = ((xcd >> 2) << 6) + loc;    // 0..127
    int q0   = qt * 32;

    int tid  = threadIdx.x;
    int wv   = tid >> 6, lane = tid & 63;
    int m16  = lane & 15, qd = lane >> 4;
    int qsub = wv >> 2;                    // 0..1 : which 16 queries
    int ksub = wv & 3;                     // QK: 16-key slice; PV: 64-chan slice

    // persistent Q fragment: B-operand [d][q], q = q0+qsub*16+m16, d = qd*8..
    short8 Qf = *(const short8*)(q_t + ((size_t)b * 4096 + q0 + qsub * 16 + m16) * 32 + qd * 8);

    // K: A-operand [k][d]; one 1KB coalesced wave load per tile
    const unsigned short* kp = k_t + ((size_t)b * 4096 + ksub * 16 + m16) * 32 + qd * 8;
    // V: B-operand [k][c] == contiguous 16B of tile-blocked [kt][c][64k]
    const unsigned short* vp = v_ws + ((size_t)b * 64 * 256 + ksub * 64 + m16) * 64 + qd * 8;

    // P LDS addressing, 16B-chunk XOR swizzle keyed on q-row (m16&7):
    //  write (8B): plain chunk = ksub*2 + qd/2, half = qd&1
    //  read (16B): plain chunk = h*4 + qd
    int widx  = m16 * 64 + (((ksub * 2 + (qd >> 1)) ^ (m16 & 7)) << 3) + ((qd & 1) << 2);
    int ridx0 = m16 * 64 + (((0 + qd) ^ (m16 & 7)) << 3);
    int ridx1 = m16 * 64 + (((4 + qd) ^ (m16 & 7)) << 3);

    f32x4 zero4 = {0.f, 0.f, 0.f, 0.f};
    f32x4 acc[4] = {zero4, zero4, zero4, zero4};
    float lsum = 0.f;

    short8 Kf = *(const short8*)kp;        // tile 0 K fragment
    kp += 2048;

    #pragma unroll 1
    for (int it = 0; it < 64; ++it) {
        unsigned short* Pz = &Pb[it & 1][qsub][0];

        // V fragments for this tile: 8 x 16B direct from L2, issued early so
        // the QK+softmax phase hides the latency (consumed after barrier)
        short8 Vf[4][2];
        #pragma unroll
        for (int ct = 0; ct < 4; ++ct) {
            Vf[ct][0] = *(const short8*)(vp + ct * 1024);
            Vf[ct][1] = *(const short8*)(vp + ct * 1024 + 32);
        }

        // S^T tile (16k x 16q): col=m16=q, row=4*qd+r=k  (single MFMA, K=32)
        f32x4 S = __builtin_amdgcn_mfma_f32_16x16x32_bf16(Kf, Qf, zero4, 0, 0, 0);

        // prefetch next tile's K while exp/pack runs
        if (it < 63) { Kf = *(const short8*)kp; kp += 2048; }

        float a0 = __builtin_amdgcn_exp2f(S.x), a1 = __builtin_amdgcn_exp2f(S.y);
        float a2 = __builtin_amdgcn_exp2f(S.z), a3 = __builtin_amdgcn_exp2f(S.w);
        lsum += (a0 + a1) + (a2 + a3);
        uint2 w; w.x = pack2bf(a0, a1); w.y = pack2bf(a2, a3);
        *(uint2*)&Pz[widx] = w;

        __syncthreads();   // P[z] complete; dbuf makes next tile's write safe

        // A-fragments: P[q=m16][k = h*32 + qd*8 ..+7], conflict-free swizzled
        short8 Ap0 = *(const short8*)&Pz[ridx0];
        short8 Ap1 = *(const short8*)&Pz[ridx1];

        acc[0] = __builtin_amdgcn_mfma_f32_16x16x32_bf16(Ap0, Vf[0][0], acc[0], 0, 0, 0);
        acc[1] = __builtin_amdgcn_mfma_f32_16x16x32_bf16(Ap0, Vf[1][0], acc[1], 0, 0, 0);
        acc[2] = __builtin_amdgcn_mfma_f32_16x16x32_bf16(Ap0, Vf[2][0], acc[2], 0, 0, 0);
        acc[3] = __builtin_amdgcn_mfma_f32_16x16x32_bf16(Ap0, Vf[3][0], acc[3], 0, 0, 0);
        acc[0] = __builtin_amdgcn_mfma_f32_16x16x32_bf16(Ap1, Vf[0][1], acc[0], 0, 0, 0);
        acc[1] = __builtin_amdgcn_mfma_f32_16x16x32_bf16(Ap1, Vf[1][1], acc[1], 0, 0, 0);
        acc[2] = __builtin_amdgcn_mfma_f32_16x16x32_bf16(Ap1, Vf[2][1], acc[2], 0, 0, 0);
        acc[3] = __builtin_amdgcn_mfma_f32_16x16x32_bf16(Ap1, Vf[3][1], acc[3], 0, 0, 0);

        vp += 16384;       // next 64-key V panel
    }

    // ---- softmax denominators: reduce over qd in-wave, over ksub via LDS ----
    lsum += __shfl_xor(lsum, 16);
    lsum += __shfl_xor(lsum, 32);
    if (lane < 16) Ls[qsub][ksub][lane] = lsum;
    __syncthreads();

    f32x4 sum4 = *(const f32x4*)&Ls[qsub][0][qd * 4];
    sum4 += *(const f32x4*)&Ls[qsub][1][qd * 4];
    sum4 += *(const f32x4*)&Ls[qsub][2][qd * 4];
    sum4 += *(const f32x4*)&Ls[qsub][3][qd * 4];
    f32x4 inv4;
    inv4.x = __builtin_amdgcn_rcpf(sum4.x);
    inv4.y = __builtin_amdgcn_rcpf(sum4.y);
    inv4.z = __builtin_amdgcn_rcpf(sum4.z);
    inv4.w = __builtin_amdgcn_rcpf(sum4.w);

    // acc layout: col=m16=c (within 16-chan tile), row=4*qd+r=q (local)
    float* ob = out + ((size_t)b * 256 + ksub * 64 + m16) * 4096 + q0 + qsub * 16 + qd * 4;
    #pragma unroll
    for (int ct = 0; ct < 4; ++ct) {
        float4 o;
        o.x = acc[ct].x * inv4.x;
        o.y = acc[ct].y * inv4.y;
        o.z = acc[ct].z * inv4.z;
        o.w = acc[ct].w * inv4.w;
        *(float4*)(ob + (size_t)ct * 16 * 4096) = o;
    }
}

// ---------------------------------------------------------------------------
// Workspace: wq 320x256 bf16 | scale/off 320 f32 | q_t,k_t [b][n][32] bf16 |
// v_ws tile-blocked [b*64+kt][256][64] bf16. Total ~10.7 MB.
// ---------------------------------------------------------------------------
extern "C" void kernel_launch(void* const* d_in, const int* in_sizes, int n_in,
                              void* d_out, int out_size, void* d_ws, size_t ws_size,
                              hipStream_t stream)
{
    const float* x1  = (const float*)d_in[0];
    const float* x2  = (const float*)d_in[1];
    const float* qw  = (const float*)d_in[2];
    const float* qb  = (const float*)d_in[3];
    const float* qg  = (const float*)d_in[4];
    const float* qbe = (const float*)d_in[5];
    const float* qm  = (const float*)d_in[6];
    const float* qv  = (const float*)d_in[7];
    const float* kw  = (const float*)d_in[8];
    const float* kb  = (const float*)d_in[9];
    const float* kg  = (const float*)d_in[10];
    const float* kbe = (const float*)d_in[11];
    const float* km  = (const float*)d_in[12];
    const float* kvv = (const float*)d_in[13];
    const float* vw  = (const float*)d_in[14];
    const float* vb  = (const float*)d_in[15];
    const float* vg  = (const float*)d_in[16];
    const float* vbe = (const float*)d_in[17];
    const float* vm  = (const float*)d_in[18];
    const float* vv  = (const float*)d_in[19];

    char* ws = (char*)d_ws;
    unsigned short* wq   = (unsigned short*)(ws + 0);
    float*          scale= (float*)(ws + 163840);
    float*          off  = (float*)(ws + 165120);
    unsigned short* q_t  = (unsigned short*)(ws + 166400);
    unsigned short* k_t  = (unsigned short*)(ws + 166400 + 1048576);
    unsigned short* v_ws = (unsigned short*)(ws + 166400 + 2097152);

    prep_kernel<<<320, 64, 0, stream>>>(qw, qb, qg, qbe, qm, qv,
                                        kw, kb, kg, kbe, km, kvv,
                                        vw, vb, vg, vbe, vm, vv,
                                        wq, scale, off);
    proj_kernel<<<1024, 256, 0, stream>>>(x1, x2, wq, scale, off, q_t, k_t, v_ws);
    flash_kernel<<<512, 512, 0, stream>>>(q_t, k_t, v_ws, (float*)d_out);
}

// Round 2
// 185.215 us; speedup vs baseline: 2.0074x; 2.0074x over previous
//
#include <hip/hip_runtime.h>

using short8   = __attribute__((ext_vector_type(8))) short;
using f32x4    = __attribute__((ext_vector_type(4))) float;
using ushort4v = __attribute__((ext_vector_type(4))) unsigned short;

#define BN_EPS 1e-5f
// log2(e)/sqrt(32): folded into q projection so softmax uses native exp2
#define ATT_SCALE_LOG2E 0.2550348347988049f

__device__ __forceinline__ unsigned short f2bf(float f) {
    union { float f; unsigned u; } v; v.f = f;
    return (unsigned short)((v.u + 0x7FFFu + ((v.u >> 16) & 1u)) >> 16);  // RNE
}

// pack two f32 -> two bf16 (round-half-up): a in low 16, b in high 16
__device__ __forceinline__ unsigned pack2bf(float a, float b) {
    union { float f; unsigned u; } ua, ub; ua.f = a; ub.f = b;
    return __builtin_amdgcn_perm(ub.u + 0x8000u, ua.u + 0x8000u, 0x07060302u);
}

// async global->LDS, 16B per lane. gp: per-lane global src. lp: wave-uniform
// LDS base (HW adds lane*16).
__device__ __forceinline__ void glds16(const void* gp, void* lp) {
    __builtin_amdgcn_global_load_lds(
        (const __attribute__((address_space(1))) unsigned*)gp,
        (__attribute__((address_space(3))) unsigned*)lp, 16, 0, 0);
}

// ---------------------------------------------------------------------------
// Kernel 0: weights -> bf16; fold conv-bias + BN into per-row (scale, offset).
// Rows: 0-31 q, 32-63 k, 64-319 v.
// ---------------------------------------------------------------------------
__global__ void prep_kernel(
    const float* __restrict__ qw, const float* __restrict__ qb,
    const float* __restrict__ qg, const float* __restrict__ qbe,
    const float* __restrict__ qm, const float* __restrict__ qv,
    const float* __restrict__ kw, const float* __restrict__ kb,
    const float* __restrict__ kg, const float* __restrict__ kbe,
    const float* __restrict__ km, const float* __restrict__ kvv,
    const float* __restrict__ vw, const float* __restrict__ vb,
    const float* __restrict__ vg, const float* __restrict__ vbe,
    const float* __restrict__ vm, const float* __restrict__ vv,
    unsigned short* __restrict__ wq, float* __restrict__ scale,
    float* __restrict__ off)
{
    int r = blockIdx.x;      // 0..319
    int t = threadIdx.x;     // 0..63
    const float *wsrc, *g, *be, *mn, *vr, *bi;
    int rl;
    if (r < 32)      { rl = r;      wsrc = qw; g = qg; be = qbe; mn = qm; vr = qv;  bi = qb; }
    else if (r < 64) { rl = r - 32; wsrc = kw; g = kg; be = kbe; mn = km; vr = kvv; bi = kb; }
    else             { rl = r - 64; wsrc = vw; g = vg; be = vbe; mn = vm; vr = vv;  bi = vb; }

    float4 w4 = *(const float4*)(wsrc + rl * 256 + t * 4);
    ushort4v o;
    o.x = f2bf(w4.x); o.y = f2bf(w4.y); o.z = f2bf(w4.z); o.w = f2bf(w4.w);
    *(ushort4v*)(wq + r * 256 + t * 4) = o;

    if (t == 0) {
        float inv = g[rl] * rsqrtf(vr[rl] + BN_EPS);
        float ofv = bi[rl] * inv + be[rl] - mn[rl] * inv;
        float s = (r < 32) ? ATT_SCALE_LOG2E : 1.0f;
        scale[r] = inv * s;
        off[r]   = ofv * s;
    }
}

// ---------------------------------------------------------------------------
// Kernel 1: projections. bx>>8 = g: 0: q(x1), 1: k(x2), 2: v ALL 256 rows (x2).
// (v-halves merged: x2 is transposed 2x total instead of 3x.)
// q_t/k_t: [b][n][32] bf16.  v_ws: TILE-BLOCKED [b*64+nt][256][64] bf16.
// ---------------------------------------------------------------------------
#define XT_PITCH 264

__global__ __launch_bounds__(256, 4) void proj_kernel(
    const float* __restrict__ x1, const float* __restrict__ x2,
    const unsigned short* __restrict__ wq,
    const float* __restrict__ scale, const float* __restrict__ off,
    unsigned short* __restrict__ q_t, unsigned short* __restrict__ k_t,
    unsigned short* __restrict__ v_ws)
{
    __shared__ __align__(16) unsigned short Xt[64 * XT_PITCH];   // 33792 B
    int bx = blockIdx.x;
    int g  = bx >> 8;        // 0,1,2
    int t2 = bx & 255;
    int nt = t2 & 63;
    int b  = t2 >> 6;
    int n0 = nt * 64;
    int tid = threadIdx.x;
    int wv = tid >> 6, lane = tid & 63;
    int m16 = lane & 15, qd = lane >> 4;

    const float* xb = ((g == 0) ? x1 : x2) + (size_t)b * 256 * 4096 + n0 + lane;

    // octet-gather transpose: n = lane, channels 8*o..8*o+7, o = wv*8+i
    #pragma unroll 2
    for (int i = 0; i < 8; ++i) {
        int o = wv * 8 + i;                       // 0..31
        const float* src = xb + (size_t)(o * 8) * 4096;
        uint4 dw;
        dw.x = pack2bf(src[0],                src[(size_t)1 * 4096]);
        dw.y = pack2bf(src[(size_t)2 * 4096], src[(size_t)3 * 4096]);
        dw.z = pack2bf(src[(size_t)4 * 4096], src[(size_t)5 * 4096]);
        dw.w = pack2bf(src[(size_t)6 * 4096], src[(size_t)7 * 4096]);
        *(uint4*)&Xt[lane * XT_PITCH + o * 8] = dw;
    }
    __syncthreads();

    f32x4 zero4 = {0.f, 0.f, 0.f, 0.f};

    if (g < 2) {
        int rb = g * 32;
        f32x4 acc0 = zero4, acc1 = zero4;
        #pragma unroll 2
        for (int s = 0; s < 8; ++s) {
            short8 w0 = *(const short8*)(wq + (size_t)(rb +      m16) * 256 + s * 32 + qd * 8);
            short8 w1 = *(const short8*)(wq + (size_t)(rb + 16 + m16) * 256 + s * 32 + qd * 8);
            short8 xf = *(const short8*)&Xt[(16 * wv + m16) * XT_PITCH + s * 32 + qd * 8];
            acc0 = __builtin_amdgcn_mfma_f32_16x16x32_bf16(w0, xf, acc0, 0, 0, 0);
            acc1 = __builtin_amdgcn_mfma_f32_16x16x32_bf16(w1, xf, acc1, 0, 0, 0);
        }
        unsigned short* dst = (g == 0) ? q_t : k_t;
        int ncol = n0 + 16 * wv + m16;
        #pragma unroll
        for (int tm = 0; tm < 2; ++tm) {
            f32x4 acc = tm ? acc1 : acc0;
            int r0 = 16 * tm + 4 * qd;
            float4 sc = *(const float4*)(scale + rb + r0);
            float4 of = *(const float4*)(off   + rb + r0);
            ushort4v o;
            o.x = f2bf(acc.x * sc.x + of.x);
            o.y = f2bf(acc.y * sc.y + of.y);
            o.z = f2bf(acc.z * sc.z + of.z);
            o.w = f2bf(acc.w * sc.w + of.w);
            *(ushort4v*)(dst + ((size_t)b * 4096 + ncol) * 32 + r0) = o;
        }
    } else {
        // v: all 256 rows from one x2 transpose
        f32x4 acc[4][4];
        #pragma unroll
        for (int rr = 0; rr < 4; ++rr)
            #pragma unroll
            for (int tm = 0; tm < 4; ++tm) acc[rr][tm] = zero4;
        #pragma unroll 1
        for (int s = 0; s < 8; ++s) {
            short8 xf[4];
            #pragma unroll
            for (int tm = 0; tm < 4; ++tm)
                xf[tm] = *(const short8*)&Xt[(16 * tm + m16) * XT_PITCH + s * 32 + qd * 8];
            #pragma unroll
            for (int rr = 0; rr < 4; ++rr) {
                short8 wf = *(const short8*)(wq + (size_t)(64 + rr * 64 + 16 * wv + m16) * 256 + s * 32 + qd * 8);
                #pragma unroll
                for (int tm = 0; tm < 4; ++tm)
                    acc[rr][tm] = __builtin_amdgcn_mfma_f32_16x16x32_bf16(xf[tm], wf, acc[rr][tm], 0, 0, 0);
            }
        }
        unsigned short* vt = v_ws + (size_t)(b * 64 + nt) * 256 * 64;
        #pragma unroll
        for (int rr = 0; rr < 4; ++rr) {
            int c = rr * 64 + 16 * wv + m16;
            float sc = scale[64 + c], of = off[64 + c];
            #pragma unroll
            for (int tm = 0; tm < 4; ++tm) {
                int nloc = 16 * tm + 4 * qd;
                ushort4v o;
                o.x = f2bf(acc[rr][tm].x * sc + of);
                o.y = f2bf(acc[rr][tm].y * sc + of);
                o.z = f2bf(acc[rr][tm].z * sc + of);
                o.w = f2bf(acc[rr][tm].w * sc + of);
                *(ushort4v*)(vt + c * 64 + nloc) = o;
            }
        }
    }
}

// ---------------------------------------------------------------------------
// Kernel 2: flash attention, S SHARED ACROSS 128 CHANNELS (2x redundancy).
// Block = 4 waves (256 thr), 64 queries x 128 channels, ALL 4096 keys.
// Grid 512 = 2cg x 4b x 64qg, XCD-bijective: phys&7 -> (cg,b) so each XCD's
// L2 holds one batch's K (256KB) + one 128c V half (1MB) + Q (256KB).
// Per 64-key tile, two raw barriers:
//   B1: s_waitcnt vmcnt(0) + s_barrier  (tile-it K/V DMA landed; issued a
//       full iteration ago -> covered). Then issue next tile's DMA (K 4KB +
//       V 16KB via glds16, source-swizzled, dest linear).
//   QK: wave kq=wv computes S^T (16k x 64q) for its key slice: 4 MFMAs,
//       16 exp2/lane (vs 32 at 4x redundancy), packs into ONE shared 8KB
//       XOR-swizzled P (single-buffered; safe between B1/B2 fences).
//   B2: s_waitcnt lgkmcnt(0) + s_barrier (NO vmcnt drain -> next tile's DMA
//       stays in flight across the barrier).
//   PV: wave cw=wv owns 32 channels x 64q: 8 Ap + 4 V b128 reads feed 16
//       MFMAs (V frags reused across 4 q-tiles). setprio(1) around MFMAs.
// All LDS access patterns bank-balanced (8 lanes per 4-bank group = 8-round
// minimum). Row sums: per-wave partials, one LDS combine in epilogue.
// ---------------------------------------------------------------------------
__global__ __launch_bounds__(256, 2) void flash_kernel(
    const unsigned short* __restrict__ q_t, const unsigned short* __restrict__ k_t,
    const unsigned short* __restrict__ v_ws, float* __restrict__ out)
{
    // Kbuf 2x4KB @0 | Vbuf 2x16KB @8192 | P 8KB @40960 | Ls 1KB @49152
    __shared__ __align__(16) unsigned char Smem[50176];

    int bx = blockIdx.x;                   // 512 blocks
    int cg = (bx >> 2) & 1;
    int b  = bx & 3;
    int qg = bx >> 3;                      // 0..63
    int q0 = qg * 64;
    int cb = cg * 128;

    int tid = threadIdx.x;
    int wv  = tid >> 6, lane = tid & 63;
    int m16 = lane & 15, qd = lane >> 4;
    int sw7 = m16 & 7, sw3 = m16 & 3;

    char* smem = (char*)Smem;
    unsigned short* Ps = (unsigned short*)(smem + 40960);
    float*          Lsh = (float*)(smem + 49152);

    // ---- DMA source offsets (swizzle folded into global src; LDS linear) ----
    int kgo, kl = wv * 1024;
    { int i = wv * 64 + lane; int row = i >> 2, pos = i & 3;
      kgo = (row * 4 + (pos ^ (row & 3))) * 16; }
    int vgo[4], vl[4];
    #pragma unroll
    for (int u = 0; u < 4; ++u) {
        int i = (wv * 4 + u) * 64 + lane; int row = i >> 3, pos = i & 7;
        vgo[u] = (row * 8 + (pos ^ (row & 7))) * 16;
        vl[u]  = (wv * 4 + u) * 1024;
    }

    const char* kbase = (const char*)k_t + (size_t)b * 262144;
    const char* vbase = (const char*)v_ws + (size_t)b * 2097152 + (size_t)cb * 128;

    // ---- persistent Q fragments (all 4 q-tiles) ----
    const unsigned short* qb = q_t + ((size_t)b * 4096 + q0) * 32;
    short8 Qf[4];
    #pragma unroll
    for (int qt = 0; qt < 4; ++qt)
        Qf[qt] = *(const short8*)(qb + (size_t)(qt * 16 + m16) * 32 + qd * 8);

    // ---- LDS read/write offsets ----
    int kro = (wv * 16 + m16) * 64 + ((qd ^ sw3) << 4);          // K frag, bytes
    int widx[4];
    #pragma unroll
    for (int qt = 0; qt < 4; ++qt)                                // P write, shorts
        widx[qt] = (qt * 16 + m16) * 64 + (((wv * 2 + (qd >> 1)) ^ sw7) << 3) + ((qd & 1) << 2);
    int vro[2];
    #pragma unroll
    for (int kc = 0; kc < 2; ++kc)                                // V frag chunk, bytes
        vro[kc] = ((kc * 4 + qd) ^ sw7) << 4;

    f32x4 zero4 = {0.f, 0.f, 0.f, 0.f};
    f32x4 acc[4][2];
    #pragma unroll
    for (int qt = 0; qt < 4; ++qt)
        #pragma unroll
        for (int ct = 0; ct < 2; ++ct) acc[qt][ct] = zero4;
    float lsum[4] = {0.f, 0.f, 0.f, 0.f};

    // prologue: stage tile 0 into buf 0
    glds16(kbase + kgo, smem + kl);
    #pragma unroll
    for (int u = 0; u < 4; ++u) glds16(vbase + vgo[u], smem + 8192 + vl[u]);

    #pragma unroll 1
    for (int it = 0; it < 64; ++it) {
        int z = it & 1;
        char* Kb = smem + z * 4096;
        char* Vb = smem + 8192 + z * 16384;

        // B1: tile-it staging complete (DMA issued one full iteration ago)
        asm volatile("s_waitcnt vmcnt(0)\n\ts_barrier" ::: "memory");

        short8 Kf = *(const short8*)(Kb + kro);

        if (it < 63) {    // stage tile it+1 into buf z^1 (readers done pre-B1)
            const char* ks = kbase + (size_t)(it + 1) * 4096;
            const char* vs = vbase + (size_t)(it + 1) * 32768;
            char* kd = smem + (z ^ 1) * 4096;
            char* vd = smem + 8192 + (z ^ 1) * 16384;
            glds16(ks + kgo, kd + kl);
            #pragma unroll
            for (int u = 0; u < 4; ++u) glds16(vs + vgo[u], vd + vl[u]);
        }

        // V fragments early (valid since B1); reused across all 4 q-tiles
        short8 Vf[2][2];
        #pragma unroll
        for (int ct = 0; ct < 2; ++ct)
            #pragma unroll
            for (int kc = 0; kc < 2; ++kc)
                Vf[ct][kc] = *(const short8*)(Vb + (wv * 32 + ct * 16 + m16) * 128 + vro[kc]);

        // ---- QK: S^T (16k x 16q) per q-tile; k = wv*16 + 4*qd + r ----
        #pragma unroll
        for (int qt = 0; qt < 4; ++qt) {
            f32x4 S = __builtin_amdgcn_mfma_f32_16x16x32_bf16(Kf, Qf[qt], zero4, 0, 0, 0);
            float a0 = __builtin_amdgcn_exp2f(S.x), a1 = __builtin_amdgcn_exp2f(S.y);
            float a2 = __builtin_amdgcn_exp2f(S.z), a3 = __builtin_amdgcn_exp2f(S.w);
            lsum[qt] += (a0 + a1) + (a2 + a3);
            uint2 w; w.x = pack2bf(a0, a1); w.y = pack2bf(a2, a3);
            *(uint2*)&Ps[widx[qt]] = w;
        }

        // B2: P complete across waves; DMA stays in flight (no vmcnt drain)
        asm volatile("s_waitcnt lgkmcnt(0)\n\ts_barrier" ::: "memory");

        __builtin_amdgcn_s_setprio(1);
        short8 Ap[4][2];
        #pragma unroll
        for (int qt = 0; qt < 4; ++qt)
            #pragma unroll
            for (int kc = 0; kc < 2; ++kc)
                Ap[qt][kc] = *(const short8*)&Ps[(qt * 16 + m16) * 64 + (((kc * 4 + qd) ^ sw7) << 3)];
        #pragma unroll
        for (int qt = 0; qt < 4; ++qt)
            #pragma unroll
            for (int ct = 0; ct < 2; ++ct) {
                acc[qt][ct] = __builtin_amdgcn_mfma_f32_16x16x32_bf16(Ap[qt][0], Vf[ct][0], acc[qt][ct], 0, 0, 0);
                acc[qt][ct] = __builtin_amdgcn_mfma_f32_16x16x32_bf16(Ap[qt][1], Vf[ct][1], acc[qt][ct], 0, 0, 0);
            }
        __builtin_amdgcn_s_setprio(0);
    }

    // ---- softmax denominators: qd-reduce in-wave, key-slice combine in LDS ----
    #pragma unroll
    for (int qt = 0; qt < 4; ++qt) {
        float l = lsum[qt];
        l += __shfl_xor(l, 16);
        l += __shfl_xor(l, 32);
        if (lane < 16) Lsh[wv * 64 + qt * 16 + lane] = l;
    }
    asm volatile("s_waitcnt lgkmcnt(0)\n\ts_barrier" ::: "memory");

    #pragma unroll
    for (int qt = 0; qt < 4; ++qt) {
        f32x4 s4 = *(const f32x4*)&Lsh[qt * 16 + qd * 4];
        s4 += *(const f32x4*)&Lsh[64  + qt * 16 + qd * 4];
        s4 += *(const f32x4*)&Lsh[128 + qt * 16 + qd * 4];
        s4 += *(const f32x4*)&Lsh[192 + qt * 16 + qd * 4];
        f32x4 inv4;
        inv4.x = __builtin_amdgcn_rcpf(s4.x);
        inv4.y = __builtin_amdgcn_rcpf(s4.y);
        inv4.z = __builtin_amdgcn_rcpf(s4.z);
        inv4.w = __builtin_amdgcn_rcpf(s4.w);
        #pragma unroll
        for (int ct = 0; ct < 2; ++ct) {
            // acc: col=m16=c-local, row=4*qd+r=q-local
            float* ob = out + ((size_t)(b * 256 + cb + wv * 32 + ct * 16 + m16)) * 4096
                            + q0 + qt * 16 + qd * 4;
            float4 o;
            o.x = acc[qt][ct].x * inv4.x;
            o.y = acc[qt][ct].y * inv4.y;
            o.z = acc[qt][ct].z * inv4.z;
            o.w = acc[qt][ct].w * inv4.w;
            *(float4*)ob = o;
        }
    }
}

// ---------------------------------------------------------------------------
// Workspace: wq 320x256 bf16 | scale/off 320 f32 | q_t,k_t [b][n][32] bf16 |
// v_ws tile-blocked [b*64+kt][256][64] bf16. Total ~10.7 MB.
// ---------------------------------------------------------------------------
extern "C" void kernel_launch(void* const* d_in, const int* in_sizes, int n_in,
                              void* d_out, int out_size, void* d_ws, size_t ws_size,
                              hipStream_t stream)
{
    const float* x1  = (const float*)d_in[0];
    const float* x2  = (const float*)d_in[1];
    const float* qw  = (const float*)d_in[2];
    const float* qb  = (const float*)d_in[3];
    const float* qg  = (const float*)d_in[4];
    const float* qbe = (const float*)d_in[5];
    const float* qm  = (const float*)d_in[6];
    const float* qv  = (const float*)d_in[7];
    const float* kw  = (const float*)d_in[8];
    const float* kb  = (const float*)d_in[9];
    const float* kg  = (const float*)d_in[10];
    const float* kbe = (const float*)d_in[11];
    const float* km  = (const float*)d_in[12];
    const float* kvv = (const float*)d_in[13];
    const float* vw  = (const float*)d_in[14];
    const float* vb  = (const float*)d_in[15];
    const float* vg  = (const float*)d_in[16];
    const float* vbe = (const float*)d_in[17];
    const float* vm  = (const float*)d_in[18];
    const float* vv  = (const float*)d_in[19];

    char* ws = (char*)d_ws;
    unsigned short* wq   = (unsigned short*)(ws + 0);
    float*          scale= (float*)(ws + 163840);
    float*          off  = (float*)(ws + 165120);
    unsigned short* q_t  = (unsigned short*)(ws + 166400);
    unsigned short* k_t  = (unsigned short*)(ws + 166400 + 1048576);
    unsigned short* v_ws = (unsigned short*)(ws + 166400 + 2097152);

    prep_kernel<<<320, 64, 0, stream>>>(qw, qb, qg, qbe, qm, qv,
                                        kw, kb, kg, kbe, km, kvv,
                                        vw, vb, vg, vbe, vm, vv,
                                        wq, scale, off);
    proj_kernel<<<768, 256, 0, stream>>>(x1, x2, wq, scale, off, q_t, k_t, v_ws);
    flash_kernel<<<512, 256, 0, stream>>>(q_t, k_t, v_ws, (float*)d_out);
}